// Round 13
// baseline (1209.484 us; speedup 1.0000x reference)
//
#include <hip/hip_runtime.h>
#include <hip/hip_cooperative_groups.h>
#include <math.h>

namespace cg = cooperative_groups;

typedef _Float16 half_t;
typedef __attribute__((ext_vector_type(2))) _Float16 half2t;
typedef __attribute__((ext_vector_type(8))) _Float16 half8;
typedef __attribute__((ext_vector_type(4))) float f32x4;

// ---------------- fp16 helpers ----------------
__device__ __forceinline__ half2t u2h2(unsigned u){ half2t h; __builtin_memcpy(&h, &u, 4); return h; }
__device__ __forceinline__ unsigned h22u(half2t h){ unsigned u; __builtin_memcpy(&u, &h, 4); return u; }
__device__ __forceinline__ unsigned packh2(float a, float b){
  half2t h; h[0] = (_Float16)a; h[1] = (_Float16)b; return h22u(h);
}

// ---------------- wave helpers (wave = 64 on gfx950) ----------------
__device__ __forceinline__ float wsumf(float v){
#pragma unroll
  for (int off = 1; off < 64; off <<= 1) v += __shfl_xor(v, off, 64);
  return v;
}

// ================= bucketed CSR build =================
__global__ void k_zerob(int* __restrict__ a, int n){
  int i = blockIdx.x * blockDim.x + threadIdx.x;
  if (i < n) a[i] = 0;
}

__global__ __launch_bounds__(256) void kb_hist(
    const int* __restrict__ dst, int* __restrict__ bsum, int E, int NB)
{
  __shared__ int cnt[512];
  int t = threadIdx.x;
  int e00 = blockIdx.x * 2048;
  for (int i = t; i < NB; i += 256) cnt[i] = 0;
  __syncthreads();
#pragma unroll
  for (int k = 0; k < 8; k++){
    int e = e00 + 256 * k + t;
    if (e < E) atomicAdd(&cnt[dst[e] >> 7], 1);
  }
  __syncthreads();
  for (int i = t; i < NB; i += 256){
    int c = cnt[i];
    if (c) atomicAdd(&bsum[i], c);
  }
}

__global__ __launch_bounds__(512) void kb_scan(
    const int* __restrict__ bsum, int* __restrict__ bb, int* __restrict__ gcur,
    int E, int NB)
{
  __shared__ int sh[512];
  int t = threadIdx.x;
  int v = (t < NB) ? bsum[t] : 0;
  sh[t] = v; __syncthreads();
  for (int s = 1; s < 512; s <<= 1){
    int u = (t >= s) ? sh[t - s] : 0;
    __syncthreads();
    sh[t] += u;
    __syncthreads();
  }
  if (t < NB){
    int ex = sh[t] - v;
    bb[t] = ex; gcur[t] = ex;
  }
  if (t == 0) bb[NB] = E;
}

__global__ __launch_bounds__(256) void kb_scat(
    const int* __restrict__ src, const int* __restrict__ dst,
    int* __restrict__ gcur, int2* __restrict__ ebuf, int E, int NB)
{
  __shared__ int cnt[512], base[512];
  int t = threadIdx.x;
  int e00 = blockIdx.x * 2048;
  for (int i = t; i < NB; i += 256) cnt[i] = 0;
  __syncthreads();
  int bk[8], sv[8], dv[8];
#pragma unroll
  for (int k = 0; k < 8; k++){
    int e = e00 + 256 * k + t;
    if (e < E){
      dv[k] = dst[e]; sv[k] = src[e];
      bk[k] = dv[k] >> 7;
      atomicAdd(&cnt[bk[k]], 1);
    } else bk[k] = -1;
  }
  __syncthreads();
  for (int i = t; i < NB; i += 256){
    int c = cnt[i];
    base[i] = c ? atomicAdd(&gcur[i], c) : 0;
    cnt[i] = 0;
  }
  __syncthreads();
#pragma unroll
  for (int k = 0; k < 8; k++){
    if (bk[k] >= 0){
      int pos = base[bk[k]] + atomicAdd(&cnt[bk[k]], 1);
      ebuf[pos] = make_int2(sv[k], dv[k]);
    }
  }
}

__global__ __launch_bounds__(256) void kb_sort(
    const int2* __restrict__ ebuf, const int* __restrict__ bb,
    int* __restrict__ ptre, int* __restrict__ srcs, int N, int E)
{
  __shared__ int cnt[128], off[128];
  int b = blockIdx.x, t = threadIdx.x;
  int e0 = bb[b], e1 = bb[b + 1];
  int nn0 = b << 7;
  if (t < 128) cnt[t] = 0;
  __syncthreads();
  for (int e = e0 + t; e < e1; e += 256)
    atomicAdd(&cnt[ebuf[e].y & 127], 1);
  __syncthreads();
  if (t < 128) off[t] = cnt[t];
  __syncthreads();
  for (int s = 1; s < 128; s <<= 1){
    int v = (t < 128 && t >= s) ? off[t - s] : 0;
    __syncthreads();
    if (t < 128) off[t] += v;
    __syncthreads();
  }
  if (t < 128){
    int ex = off[t] - cnt[t];
    off[t] = ex;
    int node = nn0 + t;
    if (node < N) ptre[node] = e0 + ex;
    cnt[t] = 0;
  }
  if (b == (int)gridDim.x - 1 && t == 0) ptre[N] = E;
  __syncthreads();
  for (int e = e0 + t; e < e1; e += 256){
    int2 ed = ebuf[e];
    int lo = ed.y & 127;
    int pos = atomicAdd(&cnt[lo], 1);
    srcs[e0 + off[lo] + pos] = ed.x;
  }
}

// ---------------- weight convert + transpose to fp16 [N][K] ----------------
__global__ void k_cvtw(const float* __restrict__ W0, const float* __restrict__ W1,
                       const float* __restrict__ W2, const float* __restrict__ Wp,
                       half_t* __restrict__ T0, half_t* __restrict__ T1,
                       half_t* __restrict__ T2, half_t* __restrict__ Tp){
  int i = blockIdx.x * 256 + threadIdx.x;
  const float* src; half_t* dst; int NN, KK, idx;
  if (i < 32768){ src = W0; dst = T0; NN = 128; KK = 256; idx = i; }
  else if (i < 49152){ src = W1; dst = T1; NN = 128; KK = 128; idx = i - 32768; }
  else if (i < 57344){ src = W2; dst = T2; NN = 64; KK = 128; idx = i - 49152; }
  else { src = Wp; dst = Tp; NN = 64; KK = 64; idx = i - 57344; }
  int nn = idx / KK, kk = idx - nn * KK;
  dst[idx] = (_Float16)src[(size_t)kk * NN + nn];
}

// ---------------- MFMA GEMM + fused el/er epilogue --------------------------
template<int NC, int NH, bool XF32>
__global__ __launch_bounds__(256) void k_gemm_m(
    const void* __restrict__ Xv, const half_t* __restrict__ Wt,
    const float* __restrict__ al, const float* __restrict__ ar,
    half_t* __restrict__ Yh, float* __restrict__ el, float* __restrict__ er,
    int n, int KD)
{
  constexpr int CT = NC / 16;
  __shared__ __align__(16) half_t xs[64 * 72];
  __shared__ __align__(16) half_t ws[NC * 72];
  int tid = threadIdx.x;
  int w = tid >> 6, lane = tid & 63;
  int m = lane & 15, q = lane >> 4;
  int n0 = blockIdx.x * 64;
  f32x4 acc[CT];
#pragma unroll
  for (int ct = 0; ct < CT; ct++) acc[ct] = (f32x4){0.f, 0.f, 0.f, 0.f};

  for (int kc = 0; kc < KD; kc += 64){
    if (XF32){
      const float* X = (const float*)Xv;
#pragma unroll
      for (int s = tid; s < 512; s += 256){
        int r = s >> 3, off = (s & 7) * 8;
        int gr = min(n0 + r, n - 1);
        const float4* g = (const float4*)(X + (size_t)gr * KD + kc + off);
        float4 v0 = g[0], v1 = g[1];
        uint4 pk = make_uint4(packh2(v0.x, v0.y), packh2(v0.z, v0.w),
                              packh2(v1.x, v1.y), packh2(v1.z, v1.w));
        *(uint4*)&xs[r * 72 + off] = pk;
      }
    } else {
      const half_t* X = (const half_t*)Xv;
#pragma unroll
      for (int s = tid; s < 512; s += 256){
        int r = s >> 3, off = (s & 7) * 8;
        int gr = min(n0 + r, n - 1);
        *(uint4*)&xs[r * 72 + off] = *(const uint4*)(X + (size_t)gr * KD + kc + off);
      }
    }
#pragma unroll
    for (int s = tid; s < NC * 8; s += 256){
      int r = s >> 3, off = (s & 7) * 8;
      *(uint4*)&ws[r * 72 + off] = *(const uint4*)(Wt + (size_t)r * KD + kc + off);
    }
    __syncthreads();
    half8 a0 = *(const half8*)&xs[(16 * w + m) * 72 + q * 8];
    half8 a1 = *(const half8*)&xs[(16 * w + m) * 72 + 32 + q * 8];
#pragma unroll
    for (int ct = 0; ct < CT; ct++){
      half8 b0 = *(const half8*)&ws[(16 * ct + m) * 72 + q * 8];
      half8 b1 = *(const half8*)&ws[(16 * ct + m) * 72 + 32 + q * 8];
      acc[ct] = __builtin_amdgcn_mfma_f32_16x16x32_f16(a0, b0, acc[ct], 0, 0, 0);
      acc[ct] = __builtin_amdgcn_mfma_f32_16x16x32_f16(a1, b1, acc[ct], 0, 0, 0);
    }
    __syncthreads();
  }

#pragma unroll
  for (int j = 0; j < 4; j++){
    int gr = n0 + 16 * w + q * 4 + j;
    if (gr < n){
#pragma unroll
      for (int ct = 0; ct < CT; ct++)
        Yh[(size_t)gr * NC + 16 * ct + m] = (_Float16)acc[ct][j];
    }
  }
  float alv[CT], arv[CT];
#pragma unroll
  for (int ct = 0; ct < CT; ct++){ alv[ct] = al[16 * ct + m]; arv[ct] = ar[16 * ct + m]; }
#pragma unroll
  for (int j = 0; j < 4; j++){
    int gr = n0 + 16 * w + q * 4 + j;
    float ev[NH], rv[NH];
    if (NH == 4){
#pragma unroll
      for (int hh = 0; hh < 4; hh++){
        ev[hh] = acc[2 * hh][j] * alv[2 * hh] + acc[2 * hh + 1][j] * alv[2 * hh + 1];
        rv[hh] = acc[2 * hh][j] * arv[2 * hh] + acc[2 * hh + 1][j] * arv[2 * hh + 1];
      }
    } else {
      ev[0] = 0.f; rv[0] = 0.f;
#pragma unroll
      for (int ct = 0; ct < CT; ct++){
        ev[0] += acc[ct][j] * alv[ct];
        rv[0] += acc[ct][j] * arv[ct];
      }
    }
#pragma unroll
    for (int off = 1; off < 16; off <<= 1){
#pragma unroll
      for (int hh = 0; hh < NH; hh++){
        ev[hh] += __shfl_xor(ev[hh], off, 64);
        rv[hh] += __shfl_xor(rv[hh], off, 64);
      }
    }
    if (m == 0 && gr < n){
#pragma unroll
      for (int hh = 0; hh < NH; hh++){
        el[(size_t)gr * NH + hh] = ev[hh];
        er[(size_t)gr * NH + hh] = rv[hh];
      }
    }
  }
}

// ---------------- edge softmax + aggregation ----------------
template<int HNUM, int MDIM, int EPI>
__global__ __launch_bounds__(256) void k_edge(
    const int* __restrict__ ptre, const int* __restrict__ srcs,
    const char* __restrict__ hb, const float* __restrict__ el,
    const float* __restrict__ er, half_t* __restrict__ outx,
    unsigned char* __restrict__ outu, float* __restrict__ wE,
    int2* __restrict__ epk, int init_w, int n)
{
  constexpr int LL = MDIM / 8;
  constexpr int EP = 64 / LL;
  constexpr int RB = MDIM * 2;
  int node = blockIdx.x * 4 + (threadIdx.x >> 6);
  if (node >= n) return;
  int lane = threadIdx.x & 63;
  int base = ptre[node], deg = ptre[node + 1] - base;

  float erv[HNUM];
  if (HNUM == 4){
    float4 t = *reinterpret_cast<const float4*>(er + node * 4);
    erv[0] = t.x; erv[1] = t.y; erv[2] = t.z; erv[3] = t.w;
  } else erv[0] = er[node];

  int l = lane % LL, g = lane / LL;
  int hidx = l >> 2;
  int bo = 16 * l;
  half2t acc2[4];
#pragma unroll
  for (int k = 0; k < 4; k++) acc2[k] = (half2t){(_Float16)0.f, (_Float16)0.f};

  float inv[HNUM];
  if (deg > 64){
    float sm[HNUM];
#pragma unroll
    for (int h = 0; h < HNUM; h++) sm[h] = 0.f;
    for (int i = lane; i < deg; i += 64){
      int s = srcs[base + i];
      float e[HNUM];
      if (HNUM == 4){
        float4 t = *reinterpret_cast<const float4*>(el + s * 4);
        e[0] = t.x; e[1] = t.y; e[2] = t.z; e[3] = t.w;
      } else e[0] = el[s];
#pragma unroll
      for (int h = 0; h < HNUM; h++){
        float v = e[h] + erv[h];
        v = v > 0.f ? v : 0.2f * v;
        sm[h] += __expf(v);
      }
    }
#pragma unroll
    for (int h = 0; h < HNUM; h++) inv[h] = 1.f / (wsumf(sm[h]) + 1e-9f);
  }

  for (int c0 = 0; c0 < deg; c0 += 64){
    int cnt = min(64, deg - c0);
    int soff = 0; unsigned pa = 0, pb2 = 0;
    float pv[HNUM];
    int s = 0;
    if (lane < cnt){
      s = srcs[base + c0 + lane];
      float e[HNUM];
      if (HNUM == 4){
        float4 t = *reinterpret_cast<const float4*>(el + s * 4);
        e[0] = t.x; e[1] = t.y; e[2] = t.z; e[3] = t.w;
      } else e[0] = el[s];
#pragma unroll
      for (int h = 0; h < HNUM; h++){
        float v = e[h] + erv[h];
        v = v > 0.f ? v : 0.2f * v;
        pv[h] = __expf(v);
      }
    } else {
#pragma unroll
      for (int h = 0; h < HNUM; h++) pv[h] = 0.f;
    }
    if (deg <= 64){
#pragma unroll
      for (int h = 0; h < HNUM; h++) inv[h] = 1.f / (wsumf(pv[h]) + 1e-9f);
    }
    if (lane < cnt){
      float a[HNUM], wsum = 0.f;
#pragma unroll
      for (int h = 0; h < HNUM; h++){ a[h] = pv[h] * inv[h]; wsum += a[h]; }
      if (HNUM == 4){ pa = packh2(a[0], a[1]); pb2 = packh2(a[2], a[3]); }
      else pa = packh2(a[0], a[0]);
      wsum *= (1.f / (3.f * HNUM));
      int eidx = base + c0 + lane;
      if (EPI == 1){
        float wtot = (wE[eidx] + wsum) * (1.f / 255.f);
        epk[eidx] = make_int2(s * 64, __float_as_int(wtot));
      } else {
        wE[eidx] = init_w ? wsum : (wE[eidx] + wsum);
      }
      soff = s * RB;
    }
    for (int j0 = 0; j0 < cnt; j0 += EP){
      int j = j0 + g;
      int so = __shfl(soff, j, 64);
      unsigned paj = (unsigned)__shfl((int)pa, j, 64);
      unsigned pbj = 0;
      if (HNUM == 4) pbj = (unsigned)__shfl((int)pb2, j, 64);
      if (j < cnt){
        unsigned a2u;
        if (HNUM == 4){
          unsigned sel = (hidx < 2) ? paj : pbj;
          unsigned hb16 = (hidx & 1) ? (sel >> 16) : (sel & 0xffffu);
          a2u = hb16 | (hb16 << 16);
        } else a2u = paj;
        half2t a2 = u2h2(a2u);
        uint4 v = *(const uint4*)(hb + (unsigned)so + bo);
        acc2[0] += a2 * u2h2(v.x);
        acc2[1] += a2 * u2h2(v.y);
        acc2[2] += a2 * u2h2(v.z);
        acc2[3] += a2 * u2h2(v.w);
      }
    }
  }

#pragma unroll
  for (int off = LL; off < 64; off <<= 1)
#pragma unroll
    for (int k = 0; k < 4; k++)
      acc2[k] += u2h2((unsigned)__shfl_xor((int)h22u(acc2[k]), off, 64));

  float o[8];
#pragma unroll
  for (int k = 0; k < 4; k++){
    o[2 * k] = (float)acc2[k][0];
    o[2 * k + 1] = (float)acc2[k][1];
  }
  if (EPI == 0){
    if (g == 0){
#pragma unroll
      for (int d = 0; d < 8; d++) o[d] = o[d] > 0.f ? o[d] : expm1f(o[d]);
      uint4 pk = make_uint4(packh2(o[0], o[1]), packh2(o[2], o[3]),
                            packh2(o[4], o[5]), packh2(o[6], o[7]));
      reinterpret_cast<uint4*>(outx + (size_t)node * MDIM)[l] = pk;
    }
  } else {
    float m8 = o[0];
#pragma unroll
    for (int d = 1; d < 8; d++) m8 = fmaxf(m8, o[d]);
#pragma unroll
    for (int off = 1; off < 8; off <<= 1) m8 = fmaxf(m8, __shfl_xor(m8, off, 64));
    float p[8], s8 = 0.f;
#pragma unroll
    for (int d = 0; d < 8; d++){ p[d] = __expf(o[d] - m8); s8 += p[d]; }
#pragma unroll
    for (int off = 1; off < 8; off <<= 1) s8 += __shfl_xor(s8, off, 64);
    float is = 255.f / s8;
    if (g == 0){
      unsigned b0 = 0, b1 = 0;
#pragma unroll
      for (int d = 0; d < 4; d++) b0 |= ((unsigned)(int)(p[d] * is + 0.5f)) << (8 * d);
#pragma unroll
      for (int d = 0; d < 4; d++) b1 |= ((unsigned)(int)(p[4 + d] * is + 0.5f)) << (8 * d);
      *reinterpret_cast<uint2*>(outu + (size_t)node * 64 + 8 * l) = make_uint2(b0, b1);
    }
  }
}

// ---------------- per-step LP kernel (fallback path, round-11) --------------
template<int FINAL>
__global__ __launch_bounds__(512) void k_lpu(
    const int* __restrict__ ptre, const int2* __restrict__ epk,
    const unsigned char* __restrict__ pb, const half_t* __restrict__ Tp,
    const float* __restrict__ bp, unsigned char* __restrict__ outu,
    float* __restrict__ outf, int n)
{
  __shared__ __align__(16) half_t xs[64 * 72];
  __shared__ __align__(16) half_t ws[64 * 72];
  __shared__ float bsh[64];
  int tid = threadIdx.x;
  int w = tid >> 6, lane = tid & 63;
  int n0 = blockIdx.x * 64;
  {
    int r = tid >> 3, off = (tid & 7) * 8;
    *(uint4*)&ws[r * 72 + off] = *(const uint4*)(Tp + r * 64 + off);
  }
  if (tid < 64) bsh[tid] = bp[tid];

  int grp = tid >> 3;
  int l8 = tid & 7;
  int st = l8 >> 2, li = l8 & 3;
  int bo = 16 * li;
  int node = n0 + grp;
  float acc[16];
#pragma unroll
  for (int c = 0; c < 16; c++) acc[c] = 0.f;

  auto accum = [&](uint4 v, float wv){
#pragma unroll
    for (int b = 0; b < 4; b++){
      unsigned u = (&v.x)[b];
      acc[4 * b + 0] += wv * (float)(u & 0xffu);
      acc[4 * b + 1] += wv * (float)((u >> 8) & 0xffu);
      acc[4 * b + 2] += wv * (float)((u >> 16) & 0xffu);
      acc[4 * b + 3] += wv * (float)((u >> 24) & 0xffu);
    }
  };

  if (node < n){
    int base = ptre[node], endd = ptre[node + 1];
    for (int j0 = base + 4 * st; j0 < endd; j0 += 8){
      int2 ee[4]; float wv[4];
#pragma unroll
      for (int k = 0; k < 4; k++){
        int j = j0 + k;
        ee[k] = epk[min(j, endd - 1)];
        wv[k] = (j < endd) ? __int_as_float(ee[k].y) : 0.f;
      }
      uint4 vv[4];
#pragma unroll
      for (int k = 0; k < 4; k++)
        vv[k] = *(const uint4*)(pb + (unsigned)ee[k].x + bo);
#pragma unroll
      for (int k = 0; k < 4; k++) accum(vv[k], wv[k]);
    }
  }
#pragma unroll
  for (int c = 0; c < 16; c++) acc[c] += __shfl_xor(acc[c], 4, 64);
  if (st == 0){
    half2t hp[8];
#pragma unroll
    for (int c = 0; c < 8; c++){
      hp[c][0] = (_Float16)acc[2 * c]; hp[c][1] = (_Float16)acc[2 * c + 1];
    }
    *(uint4*)&xs[grp * 72 + 16 * li]     = *(uint4*)&hp[0];
    *(uint4*)&xs[grp * 72 + 16 * li + 8] = *(uint4*)&hp[4];
  }
  __syncthreads();
  if (w >= 4) return;

  int m = lane & 15, q = lane >> 4;
  f32x4 macc[4];
#pragma unroll
  for (int ct = 0; ct < 4; ct++) macc[ct] = (f32x4){0.f, 0.f, 0.f, 0.f};
  half8 a0 = *(const half8*)&xs[(16 * w + m) * 72 + q * 8];
  half8 a1 = *(const half8*)&xs[(16 * w + m) * 72 + 32 + q * 8];
#pragma unroll
  for (int ct = 0; ct < 4; ct++){
    half8 b0 = *(const half8*)&ws[(16 * ct + m) * 72 + q * 8];
    half8 b1 = *(const half8*)&ws[(16 * ct + m) * 72 + 32 + q * 8];
    macc[ct] = __builtin_amdgcn_mfma_f32_16x16x32_f16(a0, b0, macc[ct], 0, 0, 0);
    macc[ct] = __builtin_amdgcn_mfma_f32_16x16x32_f16(a1, b1, macc[ct], 0, 0, 0);
  }

#pragma unroll
  for (int j = 0; j < 4; j++){
    int gr = n0 + 16 * w + q * 4 + j;
    float v[4]; float mx = -INFINITY;
#pragma unroll
    for (int ct = 0; ct < 4; ct++){
      v[ct] = macc[ct][j] + bsh[16 * ct + m];
      mx = fmaxf(mx, v[ct]);
    }
#pragma unroll
    for (int off = 1; off < 16; off <<= 1) mx = fmaxf(mx, __shfl_xor(mx, off, 64));
    float p[4], s = 0.f;
#pragma unroll
    for (int ct = 0; ct < 4; ct++){ p[ct] = __expf(v[ct] - mx); s += p[ct]; }
#pragma unroll
    for (int off = 1; off < 16; off <<= 1) s += __shfl_xor(s, off, 64);
    if (gr < n){
      if (FINAL){
        float ls = __logf(s);
#pragma unroll
        for (int ct = 0; ct < 4; ct++)
          outf[(size_t)gr * 64 + 16 * ct + m] = v[ct] - mx - ls;
      } else {
        float is = 255.f / s;
#pragma unroll
        for (int ct = 0; ct < 4; ct++)
          outu[(size_t)gr * 64 + 16 * ct + m] =
              (unsigned char)(int)(p[ct] * is + 0.5f);
      }
    }
  }
}

// ---------------- cooperative fused LP: all 10 steps, 256-thr blocks --------
// 4 waves/block; 4 lanes/node batch-4 gather (round-10 shape); all waves MFMA.
__global__ __launch_bounds__(256) void k_lp10(
    const int* __restrict__ ptre, const int2* __restrict__ epk,
    unsigned char* __restrict__ pbA, unsigned char* __restrict__ pbB,
    const half_t* __restrict__ Tp, const float* __restrict__ bp,
    float* __restrict__ outf, int n, int ntiles)
{
  cg::grid_group grid = cg::this_grid();
  __shared__ __align__(16) half_t xs[64 * 72];
  __shared__ __align__(16) half_t ws[64 * 72];
  __shared__ float bsh[64];
  int tid = threadIdx.x;
  int w = tid >> 6, lane = tid & 63;
  for (int s = tid; s < 512; s += 256){
    int r = s >> 3, off = (s & 7) * 8;
    *(uint4*)&ws[r * 72 + off] = *(const uint4*)(Tp + r * 64 + off);
  }
  if (tid < 64) bsh[tid] = bp[tid];
  __syncthreads();

  int grp = tid >> 2, l4 = tid & 3;
  int bo = 16 * l4;
  int m = lane & 15, q = lane >> 4;

  for (int st = 0; st < 10; st++){
    const unsigned char* cur = (st & 1) ? pbB : pbA;
    unsigned char* nxt = (st & 1) ? pbA : pbB;
    for (int t = blockIdx.x; t < ntiles; t += gridDim.x){
      int n0 = t * 64;
      int node = n0 + grp;
      float acc[16];
#pragma unroll
      for (int c = 0; c < 16; c++) acc[c] = 0.f;
      if (node < n){
        int j = ptre[node], endd = ptre[node + 1];
        while (j + 4 <= endd){
          int2 e0 = epk[j], e1 = epk[j + 1], e2 = epk[j + 2], e3 = epk[j + 3];
          uint4 v0 = *(const uint4*)(cur + (unsigned)e0.x + bo);
          uint4 v1 = *(const uint4*)(cur + (unsigned)e1.x + bo);
          uint4 v2 = *(const uint4*)(cur + (unsigned)e2.x + bo);
          uint4 v3 = *(const uint4*)(cur + (unsigned)e3.x + bo);
          float w0 = __int_as_float(e0.y), w1 = __int_as_float(e1.y);
          float w2 = __int_as_float(e2.y), w3 = __int_as_float(e3.y);
#pragma unroll
          for (int b = 0; b < 4; b++){
            unsigned u0 = (&v0.x)[b], u1 = (&v1.x)[b], u2 = (&v2.x)[b], u3 = (&v3.x)[b];
#pragma unroll
            for (int c = 0; c < 4; c++){
              int sh = 8 * c;
              acc[4 * b + c] += w0 * (float)((u0 >> sh) & 0xffu)
                              + w1 * (float)((u1 >> sh) & 0xffu)
                              + w2 * (float)((u2 >> sh) & 0xffu)
                              + w3 * (float)((u3 >> sh) & 0xffu);
            }
          }
          j += 4;
        }
        while (j < endd){
          int2 ep = epk[j];
          uint4 v = *(const uint4*)(cur + (unsigned)ep.x + bo);
          float wv = __int_as_float(ep.y);
#pragma unroll
          for (int b = 0; b < 4; b++){
            unsigned u = (&v.x)[b];
#pragma unroll
            for (int c = 0; c < 4; c++)
              acc[4 * b + c] += wv * (float)((u >> (8 * c)) & 0xffu);
          }
          j++;
        }
      }
      {
        half2t hp[8];
#pragma unroll
        for (int c = 0; c < 8; c++){
          hp[c][0] = (_Float16)acc[2 * c]; hp[c][1] = (_Float16)acc[2 * c + 1];
        }
        *(uint4*)&xs[grp * 72 + 16 * l4]     = *(uint4*)&hp[0];
        *(uint4*)&xs[grp * 72 + 16 * l4 + 8] = *(uint4*)&hp[4];
      }
      __syncthreads();
      {
        f32x4 macc[4];
#pragma unroll
        for (int ct = 0; ct < 4; ct++) macc[ct] = (f32x4){0.f, 0.f, 0.f, 0.f};
        half8 a0 = *(const half8*)&xs[(16 * w + m) * 72 + q * 8];
        half8 a1 = *(const half8*)&xs[(16 * w + m) * 72 + 32 + q * 8];
#pragma unroll
        for (int ct = 0; ct < 4; ct++){
          half8 b0 = *(const half8*)&ws[(16 * ct + m) * 72 + q * 8];
          half8 b1 = *(const half8*)&ws[(16 * ct + m) * 72 + 32 + q * 8];
          macc[ct] = __builtin_amdgcn_mfma_f32_16x16x32_f16(a0, b0, macc[ct], 0, 0, 0);
          macc[ct] = __builtin_amdgcn_mfma_f32_16x16x32_f16(a1, b1, macc[ct], 0, 0, 0);
        }
#pragma unroll
        for (int j = 0; j < 4; j++){
          int gr = n0 + 16 * w + q * 4 + j;
          float v[4]; float mx = -INFINITY;
#pragma unroll
          for (int ct = 0; ct < 4; ct++){
            v[ct] = macc[ct][j] + bsh[16 * ct + m];
            mx = fmaxf(mx, v[ct]);
          }
#pragma unroll
          for (int off = 1; off < 16; off <<= 1) mx = fmaxf(mx, __shfl_xor(mx, off, 64));
          float p[4], s = 0.f;
#pragma unroll
          for (int ct = 0; ct < 4; ct++){ p[ct] = __expf(v[ct] - mx); s += p[ct]; }
#pragma unroll
          for (int off = 1; off < 16; off <<= 1) s += __shfl_xor(s, off, 64);
          if (gr < n){
            if (st == 9){
              float ls = __logf(s);
#pragma unroll
              for (int ct = 0; ct < 4; ct++)
                outf[(size_t)gr * 64 + 16 * ct + m] = v[ct] - mx - ls;
            } else {
              float is = 255.f / s;
#pragma unroll
              for (int ct = 0; ct < 4; ct++)
                nxt[(size_t)gr * 64 + 16 * ct + m] =
                    (unsigned char)(int)(p[ct] * is + 0.5f);
            }
          }
        }
      }
      __syncthreads();
    }
    __threadfence();
    grid.sync();
  }
}

// ---------------- launch ----------------
extern "C" void kernel_launch(void* const* d_in, const int* in_sizes, int n_in,
                              void* d_out, int out_size, void* d_ws, size_t ws_size,
                              hipStream_t stream) {
  const float* feat = (const float*)d_in[0];
  const int*   src  = (const int*)d_in[1];
  const int*   dst  = (const int*)d_in[2];
  const float* W0   = (const float*)d_in[3];
  const float* al0  = (const float*)d_in[4];
  const float* ar0  = (const float*)d_in[5];
  const float* W1   = (const float*)d_in[6];
  const float* al1  = (const float*)d_in[7];
  const float* ar1  = (const float*)d_in[8];
  const float* W2   = (const float*)d_in[9];
  const float* al2  = (const float*)d_in[10];
  const float* ar2  = (const float*)d_in[11];
  const float* Wp   = (const float*)d_in[12];
  const float* bp   = (const float*)d_in[13];
  float* out = (float*)d_out;

  const int N = in_sizes[0] / 256;
  const int E = in_sizes[1];
  const int NB = (N + 127) / 128;

  char* p = (char*)d_ws;
  auto carve = [&](size_t bytes) -> void* {
    void* r = (void*)p;
    p += (bytes + 255) & ~(size_t)255;
    return r;
  };
  int*   ptr_i = (int*)carve((size_t)(N + 1) * 4);
  int*   bsum  = (int*)carve((size_t)NB * 4);
  int*   bb    = (int*)carve((size_t)(NB + 1) * 4);
  int*   gcur  = (int*)carve((size_t)NB * 4);
  int*   srcs  = (int*)carve((size_t)E * 4);
  float* wE    = (float*)carve((size_t)E * 4);
  int2*  epk   = (int2*)carve((size_t)E * 8);
  half_t* hb   = (half_t*)carve((size_t)N * 128 * 2);
  half_t* xb   = (half_t*)carve((size_t)N * 128 * 2);
  float* el    = (float*)carve((size_t)N * 4 * 4);
  float* er    = (float*)carve((size_t)N * 4 * 4);
  unsigned char* pbA = (unsigned char*)carve((size_t)N * 64);
  unsigned char* pbB = (unsigned char*)carve((size_t)N * 64);
  half_t* T0   = (half_t*)carve(32768 * 2);
  half_t* T1   = (half_t*)carve(16384 * 2);
  half_t* T2   = (half_t*)carve(8192 * 2);
  half_t* Tp   = (half_t*)carve(4096 * 2);
  int2* ebuf = epk;
  (void)ws_size; (void)n_in; (void)out_size;

  // ---- bucketed CSR build + weight conversion ----
  const int EB = (E + 2047) / 2048;
  k_zerob<<<(NB + 255) / 256, 256, 0, stream>>>(bsum, NB);
  kb_hist<<<EB, 256, 0, stream>>>(dst, bsum, E, NB);
  kb_scan<<<1, 512, 0, stream>>>(bsum, bb, gcur, E, NB);
  kb_scat<<<EB, 256, 0, stream>>>(src, dst, gcur, ebuf, E, NB);
  kb_sort<<<NB, 256, 0, stream>>>(ebuf, bb, ptr_i, srcs, N, E);
  k_cvtw<<<240, 256, 0, stream>>>(W0, W1, W2, Wp, T0, T1, T2, Tp);

  const int GG = (N + 63) / 64;
  const int GE = (N + 3) / 4;
  // ---- layer 0: 256 -> [4,32] ----
  k_gemm_m<128, 4, true><<<GG, 256, 0, stream>>>(feat, T0, al0, ar0, hb, el, er, N, 256);
  k_edge<4, 128, 0><<<GE, 256, 0, stream>>>(ptr_i, srcs, (const char*)hb, el, er,
                                            xb, nullptr, wE, nullptr, 1, N);
  // ---- layer 1: 128 -> [4,32] ----
  k_gemm_m<128, 4, false><<<GG, 256, 0, stream>>>(xb, T1, al1, ar1, hb, el, er, N, 128);
  k_edge<4, 128, 0><<<GE, 256, 0, stream>>>(ptr_i, srcs, (const char*)hb, el, er,
                                            xb, nullptr, wE, nullptr, 0, N);
  // ---- layer 2: 128 -> [1,64] (writes u8 pseudo + epk) ----
  k_gemm_m<64, 1, false><<<GG, 256, 0, stream>>>(xb, T2, al2, ar2, hb, el, er, N, 128);
  k_edge<1, 64, 1><<<GE, 256, 0, stream>>>(ptr_i, srcs, (const char*)hb, el, er,
                                           nullptr, pbA, wE, epk, 0, N);

  // ---- LP steps: cooperative single kernel, fallback to 10 launches ----
  int ntiles = GG;
  int occ = 0;
  hipError_t oerr = hipOccupancyMaxActiveBlocksPerMultiprocessor(
      &occ, (const void*)k_lp10, 256, 0);
  int grid = (oerr == hipSuccess && occ > 0) ? occ * 256 : 0;
  if (grid > ntiles) grid = ntiles;
  hipError_t lerr = hipErrorInvalidValue;
  if (grid > 0){
    void* args[] = { (void*)&ptr_i, (void*)&epk, (void*)&pbA, (void*)&pbB,
                     (void*)&Tp, (void*)&bp, (void*)&out, (void*)&N, (void*)&ntiles };
    lerr = hipLaunchCooperativeKernel((void*)k_lp10, dim3(grid), dim3(256),
                                      args, 0, stream);
  }
  if (lerr != hipSuccess){
    // fallback: proven 10-launch loop (round-11 k_lpu)
    unsigned char* cur = pbA; unsigned char* nxt = pbB;
    for (int st = 0; st < 10; st++){
      if (st == 9)
        k_lpu<1><<<GG, 512, 0, stream>>>(ptr_i, epk, cur, Tp, bp, nullptr, out, N);
      else
        k_lpu<0><<<GG, 512, 0, stream>>>(ptr_i, epk, cur, Tp, bp, nxt, nullptr, N);
      unsigned char* t = cur; cur = nxt; nxt = t;
    }
  }
}

// Round 14
// 522.202 us; speedup vs baseline: 2.3161x; 2.3161x over previous
//
#include <hip/hip_runtime.h>
#include <math.h>

typedef _Float16 half_t;
typedef __attribute__((ext_vector_type(2))) _Float16 half2t;
typedef __attribute__((ext_vector_type(8))) _Float16 half8;
typedef __attribute__((ext_vector_type(4))) float f32x4;

// ---------------- fp16 helpers ----------------
__device__ __forceinline__ half2t u2h2(unsigned u){ half2t h; __builtin_memcpy(&h, &u, 4); return h; }
__device__ __forceinline__ unsigned h22u(half2t h){ unsigned u; __builtin_memcpy(&u, &h, 4); return u; }
__device__ __forceinline__ unsigned packh2(float a, float b){
  half2t h; h[0] = (_Float16)a; h[1] = (_Float16)b; return h22u(h);
}

// ---------------- wave helpers (wave = 64 on gfx950) ----------------
__device__ __forceinline__ float wsumf(float v){
#pragma unroll
  for (int off = 1; off < 64; off <<= 1) v += __shfl_xor(v, off, 64);
  return v;
}

// ================= bucketed CSR build =================
__global__ void k_zerob(int* __restrict__ a, int n){
  int i = blockIdx.x * blockDim.x + threadIdx.x;
  if (i < n) a[i] = 0;
}

__global__ __launch_bounds__(256) void kb_hist(
    const int* __restrict__ dst, int* __restrict__ bsum, int E, int NB)
{
  __shared__ int cnt[512];
  int t = threadIdx.x;
  int e00 = blockIdx.x * 2048;
  for (int i = t; i < NB; i += 256) cnt[i] = 0;
  __syncthreads();
#pragma unroll
  for (int k = 0; k < 8; k++){
    int e = e00 + 256 * k + t;
    if (e < E) atomicAdd(&cnt[dst[e] >> 7], 1);
  }
  __syncthreads();
  for (int i = t; i < NB; i += 256){
    int c = cnt[i];
    if (c) atomicAdd(&bsum[i], c);
  }
}

__global__ __launch_bounds__(512) void kb_scan(
    const int* __restrict__ bsum, int* __restrict__ bb, int* __restrict__ gcur,
    int E, int NB)
{
  __shared__ int sh[512];
  int t = threadIdx.x;
  int v = (t < NB) ? bsum[t] : 0;
  sh[t] = v; __syncthreads();
  for (int s = 1; s < 512; s <<= 1){
    int u = (t >= s) ? sh[t - s] : 0;
    __syncthreads();
    sh[t] += u;
    __syncthreads();
  }
  if (t < NB){
    int ex = sh[t] - v;
    bb[t] = ex; gcur[t] = ex;
  }
  if (t == 0) bb[NB] = E;
}

__global__ __launch_bounds__(256) void kb_scat(
    const int* __restrict__ src, const int* __restrict__ dst,
    int* __restrict__ gcur, int2* __restrict__ ebuf, int E, int NB)
{
  __shared__ int cnt[512], base[512];
  int t = threadIdx.x;
  int e00 = blockIdx.x * 2048;
  for (int i = t; i < NB; i += 256) cnt[i] = 0;
  __syncthreads();
  int bk[8], sv[8], dv[8];
#pragma unroll
  for (int k = 0; k < 8; k++){
    int e = e00 + 256 * k + t;
    if (e < E){
      dv[k] = dst[e]; sv[k] = src[e];
      bk[k] = dv[k] >> 7;
      atomicAdd(&cnt[bk[k]], 1);
    } else bk[k] = -1;
  }
  __syncthreads();
  for (int i = t; i < NB; i += 256){
    int c = cnt[i];
    base[i] = c ? atomicAdd(&gcur[i], c) : 0;
    cnt[i] = 0;
  }
  __syncthreads();
#pragma unroll
  for (int k = 0; k < 8; k++){
    if (bk[k] >= 0){
      int pos = base[bk[k]] + atomicAdd(&cnt[bk[k]], 1);
      ebuf[pos] = make_int2(sv[k], dv[k]);
    }
  }
}

__global__ __launch_bounds__(256) void kb_sort(
    const int2* __restrict__ ebuf, const int* __restrict__ bb,
    int* __restrict__ ptre, int* __restrict__ srcs, int N, int E)
{
  __shared__ int cnt[128], off[128];
  int b = blockIdx.x, t = threadIdx.x;
  int e0 = bb[b], e1 = bb[b + 1];
  int nn0 = b << 7;
  if (t < 128) cnt[t] = 0;
  __syncthreads();
  for (int e = e0 + t; e < e1; e += 256)
    atomicAdd(&cnt[ebuf[e].y & 127], 1);
  __syncthreads();
  if (t < 128) off[t] = cnt[t];
  __syncthreads();
  for (int s = 1; s < 128; s <<= 1){
    int v = (t < 128 && t >= s) ? off[t - s] : 0;
    __syncthreads();
    if (t < 128) off[t] += v;
    __syncthreads();
  }
  if (t < 128){
    int ex = off[t] - cnt[t];
    off[t] = ex;
    int node = nn0 + t;
    if (node < N) ptre[node] = e0 + ex;
    cnt[t] = 0;
  }
  if (b == (int)gridDim.x - 1 && t == 0) ptre[N] = E;
  __syncthreads();
  for (int e = e0 + t; e < e1; e += 256){
    int2 ed = ebuf[e];
    int lo = ed.y & 127;
    int pos = atomicAdd(&cnt[lo], 1);
    srcs[e0 + off[lo] + pos] = ed.x;
  }
}

// ---------------- weight convert + transpose to fp16 [N][K] ----------------
__global__ void k_cvtw(const float* __restrict__ W0, const float* __restrict__ W1,
                       const float* __restrict__ W2, const float* __restrict__ Wp,
                       half_t* __restrict__ T0, half_t* __restrict__ T1,
                       half_t* __restrict__ T2, half_t* __restrict__ Tp){
  int i = blockIdx.x * 256 + threadIdx.x;
  const float* src; half_t* dst; int NN, KK, idx;
  if (i < 32768){ src = W0; dst = T0; NN = 128; KK = 256; idx = i; }
  else if (i < 49152){ src = W1; dst = T1; NN = 128; KK = 128; idx = i - 32768; }
  else if (i < 57344){ src = W2; dst = T2; NN = 64; KK = 128; idx = i - 49152; }
  else { src = Wp; dst = Tp; NN = 64; KK = 64; idx = i - 57344; }
  int nn = idx / KK, kk = idx - nn * KK;
  dst[idx] = (_Float16)src[(size_t)kk * NN + nn];
}

// ---------------- MFMA GEMM + fused el/er epilogue --------------------------
template<int NC, int NH, bool XF32>
__global__ __launch_bounds__(256) void k_gemm_m(
    const void* __restrict__ Xv, const half_t* __restrict__ Wt,
    const float* __restrict__ al, const float* __restrict__ ar,
    half_t* __restrict__ Yh, float* __restrict__ el, float* __restrict__ er,
    int n, int KD)
{
  constexpr int CT = NC / 16;
  __shared__ __align__(16) half_t xs[64 * 72];
  __shared__ __align__(16) half_t ws[NC * 72];
  int tid = threadIdx.x;
  int w = tid >> 6, lane = tid & 63;
  int m = lane & 15, q = lane >> 4;
  int n0 = blockIdx.x * 64;
  f32x4 acc[CT];
#pragma unroll
  for (int ct = 0; ct < CT; ct++) acc[ct] = (f32x4){0.f, 0.f, 0.f, 0.f};

  for (int kc = 0; kc < KD; kc += 64){
    if (XF32){
      const float* X = (const float*)Xv;
#pragma unroll
      for (int s = tid; s < 512; s += 256){
        int r = s >> 3, off = (s & 7) * 8;
        int gr = min(n0 + r, n - 1);
        const float4* g = (const float4*)(X + (size_t)gr * KD + kc + off);
        float4 v0 = g[0], v1 = g[1];
        uint4 pk = make_uint4(packh2(v0.x, v0.y), packh2(v0.z, v0.w),
                              packh2(v1.x, v1.y), packh2(v1.z, v1.w));
        *(uint4*)&xs[r * 72 + off] = pk;
      }
    } else {
      const half_t* X = (const half_t*)Xv;
#pragma unroll
      for (int s = tid; s < 512; s += 256){
        int r = s >> 3, off = (s & 7) * 8;
        int gr = min(n0 + r, n - 1);
        *(uint4*)&xs[r * 72 + off] = *(const uint4*)(X + (size_t)gr * KD + kc + off);
      }
    }
#pragma unroll
    for (int s = tid; s < NC * 8; s += 256){
      int r = s >> 3, off = (s & 7) * 8;
      *(uint4*)&ws[r * 72 + off] = *(const uint4*)(Wt + (size_t)r * KD + kc + off);
    }
    __syncthreads();
    half8 a0 = *(const half8*)&xs[(16 * w + m) * 72 + q * 8];
    half8 a1 = *(const half8*)&xs[(16 * w + m) * 72 + 32 + q * 8];
#pragma unroll
    for (int ct = 0; ct < CT; ct++){
      half8 b0 = *(const half8*)&ws[(16 * ct + m) * 72 + q * 8];
      half8 b1 = *(const half8*)&ws[(16 * ct + m) * 72 + 32 + q * 8];
      acc[ct] = __builtin_amdgcn_mfma_f32_16x16x32_f16(a0, b0, acc[ct], 0, 0, 0);
      acc[ct] = __builtin_amdgcn_mfma_f32_16x16x32_f16(a1, b1, acc[ct], 0, 0, 0);
    }
    __syncthreads();
  }

#pragma unroll
  for (int j = 0; j < 4; j++){
    int gr = n0 + 16 * w + q * 4 + j;
    if (gr < n){
#pragma unroll
      for (int ct = 0; ct < CT; ct++)
        Yh[(size_t)gr * NC + 16 * ct + m] = (_Float16)acc[ct][j];
    }
  }
  float alv[CT], arv[CT];
#pragma unroll
  for (int ct = 0; ct < CT; ct++){ alv[ct] = al[16 * ct + m]; arv[ct] = ar[16 * ct + m]; }
#pragma unroll
  for (int j = 0; j < 4; j++){
    int gr = n0 + 16 * w + q * 4 + j;
    float ev[NH], rv[NH];
    if (NH == 4){
#pragma unroll
      for (int hh = 0; hh < 4; hh++){
        ev[hh] = acc[2 * hh][j] * alv[2 * hh] + acc[2 * hh + 1][j] * alv[2 * hh + 1];
        rv[hh] = acc[2 * hh][j] * arv[2 * hh] + acc[2 * hh + 1][j] * arv[2 * hh + 1];
      }
    } else {
      ev[0] = 0.f; rv[0] = 0.f;
#pragma unroll
      for (int ct = 0; ct < CT; ct++){
        ev[0] += acc[ct][j] * alv[ct];
        rv[0] += acc[ct][j] * arv[ct];
      }
    }
#pragma unroll
    for (int off = 1; off < 16; off <<= 1){
#pragma unroll
      for (int hh = 0; hh < NH; hh++){
        ev[hh] += __shfl_xor(ev[hh], off, 64);
        rv[hh] += __shfl_xor(rv[hh], off, 64);
      }
    }
    if (m == 0 && gr < n){
#pragma unroll
      for (int hh = 0; hh < NH; hh++){
        el[(size_t)gr * NH + hh] = ev[hh];
        er[(size_t)gr * NH + hh] = rv[hh];
      }
    }
  }
}

// ---------------- edge softmax + aggregation (round-11, passing) ------------
template<int HNUM, int MDIM, int EPI>
__global__ __launch_bounds__(256) void k_edge(
    const int* __restrict__ ptre, const int* __restrict__ srcs,
    const char* __restrict__ hb, const float* __restrict__ el,
    const float* __restrict__ er, half_t* __restrict__ outx,
    unsigned char* __restrict__ outu, float* __restrict__ wE,
    int2* __restrict__ epk, int init_w, int n)
{
  constexpr int LL = MDIM / 8;
  constexpr int EP = 64 / LL;
  constexpr int RB = MDIM * 2;
  int node = blockIdx.x * 4 + (threadIdx.x >> 6);
  if (node >= n) return;
  int lane = threadIdx.x & 63;
  int base = ptre[node], deg = ptre[node + 1] - base;

  float erv[HNUM];
  if (HNUM == 4){
    float4 t = *reinterpret_cast<const float4*>(er + node * 4);
    erv[0] = t.x; erv[1] = t.y; erv[2] = t.z; erv[3] = t.w;
  } else erv[0] = er[node];

  int l = lane % LL, g = lane / LL;
  int hidx = l >> 2;
  int bo = 16 * l;
  half2t acc2[4];
#pragma unroll
  for (int k = 0; k < 4; k++) acc2[k] = (half2t){(_Float16)0.f, (_Float16)0.f};

  float inv[HNUM];
  if (deg > 64){
    float sm[HNUM];
#pragma unroll
    for (int h = 0; h < HNUM; h++) sm[h] = 0.f;
    for (int i = lane; i < deg; i += 64){
      int s = srcs[base + i];
      float e[HNUM];
      if (HNUM == 4){
        float4 t = *reinterpret_cast<const float4*>(el + s * 4);
        e[0] = t.x; e[1] = t.y; e[2] = t.z; e[3] = t.w;
      } else e[0] = el[s];
#pragma unroll
      for (int h = 0; h < HNUM; h++){
        float v = e[h] + erv[h];
        v = v > 0.f ? v : 0.2f * v;
        sm[h] += __expf(v);
      }
    }
#pragma unroll
    for (int h = 0; h < HNUM; h++) inv[h] = 1.f / (wsumf(sm[h]) + 1e-9f);
  }

  for (int c0 = 0; c0 < deg; c0 += 64){
    int cnt = min(64, deg - c0);
    int soff = 0; unsigned pa = 0, pb2 = 0;
    float pv[HNUM];
    int s = 0;
    if (lane < cnt){
      s = srcs[base + c0 + lane];
      float e[HNUM];
      if (HNUM == 4){
        float4 t = *reinterpret_cast<const float4*>(el + s * 4);
        e[0] = t.x; e[1] = t.y; e[2] = t.z; e[3] = t.w;
      } else e[0] = el[s];
#pragma unroll
      for (int h = 0; h < HNUM; h++){
        float v = e[h] + erv[h];
        v = v > 0.f ? v : 0.2f * v;
        pv[h] = __expf(v);
      }
    } else {
#pragma unroll
      for (int h = 0; h < HNUM; h++) pv[h] = 0.f;
    }
    if (deg <= 64){
#pragma unroll
      for (int h = 0; h < HNUM; h++) inv[h] = 1.f / (wsumf(pv[h]) + 1e-9f);
    }
    if (lane < cnt){
      float a[HNUM], wsum = 0.f;
#pragma unroll
      for (int h = 0; h < HNUM; h++){ a[h] = pv[h] * inv[h]; wsum += a[h]; }
      if (HNUM == 4){ pa = packh2(a[0], a[1]); pb2 = packh2(a[2], a[3]); }
      else pa = packh2(a[0], a[0]);
      wsum *= (1.f / (3.f * HNUM));
      int eidx = base + c0 + lane;
      if (EPI == 1){
        float wtot = (wE[eidx] + wsum) * (1.f / 255.f);
        epk[eidx] = make_int2(s * 64, __float_as_int(wtot));
      } else {
        wE[eidx] = init_w ? wsum : (wE[eidx] + wsum);
      }
      soff = s * RB;
    }
    for (int j0 = 0; j0 < cnt; j0 += EP){
      int j = j0 + g;
      int so = __shfl(soff, j, 64);
      unsigned paj = (unsigned)__shfl((int)pa, j, 64);
      unsigned pbj = 0;
      if (HNUM == 4) pbj = (unsigned)__shfl((int)pb2, j, 64);
      if (j < cnt){
        unsigned a2u;
        if (HNUM == 4){
          unsigned sel = (hidx < 2) ? paj : pbj;
          unsigned hb16 = (hidx & 1) ? (sel >> 16) : (sel & 0xffffu);
          a2u = hb16 | (hb16 << 16);
        } else a2u = paj;
        half2t a2 = u2h2(a2u);
        uint4 v = *(const uint4*)(hb + (unsigned)so + bo);
        acc2[0] += a2 * u2h2(v.x);
        acc2[1] += a2 * u2h2(v.y);
        acc2[2] += a2 * u2h2(v.z);
        acc2[3] += a2 * u2h2(v.w);
      }
    }
  }

#pragma unroll
  for (int off = LL; off < 64; off <<= 1)
#pragma unroll
    for (int k = 0; k < 4; k++)
      acc2[k] += u2h2((unsigned)__shfl_xor((int)h22u(acc2[k]), off, 64));

  float o[8];
#pragma unroll
  for (int k = 0; k < 4; k++){
    o[2 * k] = (float)acc2[k][0];
    o[2 * k + 1] = (float)acc2[k][1];
  }
  if (EPI == 0){
    if (g == 0){
#pragma unroll
      for (int d = 0; d < 8; d++) o[d] = o[d] > 0.f ? o[d] : expm1f(o[d]);
      uint4 pk = make_uint4(packh2(o[0], o[1]), packh2(o[2], o[3]),
                            packh2(o[4], o[5]), packh2(o[6], o[7]));
      reinterpret_cast<uint4*>(outx + (size_t)node * MDIM)[l] = pk;
    }
  } else {
    float m8 = o[0];
#pragma unroll
    for (int d = 1; d < 8; d++) m8 = fmaxf(m8, o[d]);
#pragma unroll
    for (int off = 1; off < 8; off <<= 1) m8 = fmaxf(m8, __shfl_xor(m8, off, 64));
    float p[8], s8 = 0.f;
#pragma unroll
    for (int d = 0; d < 8; d++){ p[d] = __expf(o[d] - m8); s8 += p[d]; }
#pragma unroll
    for (int off = 1; off < 8; off <<= 1) s8 += __shfl_xor(s8, off, 64);
    float is = 255.f / s8;
    if (g == 0){
      unsigned b0 = 0, b1 = 0;
#pragma unroll
      for (int d = 0; d < 4; d++) b0 |= ((unsigned)(int)(p[d] * is + 0.5f)) << (8 * d);
#pragma unroll
      for (int d = 0; d < 4; d++) b1 |= ((unsigned)(int)(p[4 + d] * is + 0.5f)) << (8 * d);
      *reinterpret_cast<uint2*>(outu + (size_t)node * 64 + 8 * l) = make_uint2(b0, b1);
    }
  }
}

// ---------------- LP step: wave-autonomous (no LDS, no barriers) ------------
// Each wave owns 16 nodes. Gather: 4 lanes/node, batch-8 clamped (8 gathers
// in flight). A-fragments built via 16 in-register shuffles. Wp B-fragments
// + bias loaded from L2-hot global once per wave. 8 MFMAs + softmax epilogue.
template<int FINAL>
__global__ __launch_bounds__(256) void k_lpw(
    const int* __restrict__ ptre, const int2* __restrict__ epk,
    const unsigned char* __restrict__ pb, const half_t* __restrict__ Tp,
    const float* __restrict__ bp, unsigned char* __restrict__ outu,
    float* __restrict__ outf, int n)
{
  int tid = threadIdx.x;
  int w = tid >> 6, lane = tid & 63;
  int wbase = (blockIdx.x * 4 + w) * 16;
  if (wbase >= n) return;
  int mD = lane & 15, qD = lane >> 4;

  // B fragments + bias (per-lane, from global; Tp is 8 KB -> L2 broadcast)
  half8 bf0[4], bf1[4]; float bv[4];
#pragma unroll
  for (int ct = 0; ct < 4; ct++){
    bf0[ct] = *(const half8*)(Tp + (16 * ct + mD) * 64 + qD * 8);
    bf1[ct] = *(const half8*)(Tp + (16 * ct + mD) * 64 + 32 + qD * 8);
    bv[ct] = bp[16 * ct + mD];
  }

  // ---- gather: node = wbase + (lane>>2); lane l4 covers classes 16*l4.. ----
  int gnode = wbase + (lane >> 2);
  int l4 = lane & 3, bo = 16 * l4;
  float acc[16];
#pragma unroll
  for (int c = 0; c < 16; c++) acc[c] = 0.f;
  if (gnode < n){
    int jb = ptre[gnode], endd = ptre[gnode + 1];
    for (int j0 = jb; j0 < endd; j0 += 8){
      int2 ee[8]; float wv[8];
#pragma unroll
      for (int k = 0; k < 8; k++){
        int jj = j0 + k;
        ee[k] = epk[min(jj, endd - 1)];
        wv[k] = (jj < endd) ? __int_as_float(ee[k].y) : 0.f;
      }
      uint4 vv[8];
#pragma unroll
      for (int k = 0; k < 8; k++)
        vv[k] = *(const uint4*)(pb + (unsigned)ee[k].x + bo);
#pragma unroll
      for (int k = 0; k < 8; k++){
        float wvk = wv[k];
#pragma unroll
        for (int b = 0; b < 4; b++){
          unsigned u = (&vv[k].x)[b];
          acc[4 * b + 0] += wvk * (float)(u & 0xffu);
          acc[4 * b + 1] += wvk * (float)((u >> 8) & 0xffu);
          acc[4 * b + 2] += wvk * (float)((u >> 16) & 0xffu);
          acc[4 * b + 3] += wvk * (float)((u >> 24) & 0xffu);
        }
      }
    }
  }

  // ---- pack to half2 dwords: d[c] = classes 16*l4 + {2c, 2c+1} ----
  unsigned d[8];
#pragma unroll
  for (int c = 0; c < 8; c++) d[c] = packh2(acc[2 * c], acc[2 * c + 1]);

  // ---- redistribute to A-fragment layout via shuffles ----
  // dest lane (qD,mD) wants: a0 = classes 8qD..8qD+7, a1 = classes 32+8qD..
  // source for a0: lane mD*4 + (qD>>1); for a1: +2. half select by qD&1.
  int s0 = mD * 4 + (qD >> 1);
  int s1 = s0 + 2;
  int hi = qD & 1;
  unsigned a0w[4], a1w[4];
#pragma unroll
  for (int j = 0; j < 4; j++){
    unsigned lo0 = (unsigned)__shfl((int)d[j], s0, 64);
    unsigned hi0 = (unsigned)__shfl((int)d[4 + j], s0, 64);
    a0w[j] = hi ? hi0 : lo0;
    unsigned lo1 = (unsigned)__shfl((int)d[j], s1, 64);
    unsigned hi1 = (unsigned)__shfl((int)d[4 + j], s1, 64);
    a1w[j] = hi ? hi1 : lo1;
  }
  half8 a0, a1;
  __builtin_memcpy(&a0, a0w, 16);
  __builtin_memcpy(&a1, a1w, 16);

  // ---- 64x64 MFMA vs Wp ----
  f32x4 macc[4];
#pragma unroll
  for (int ct = 0; ct < 4; ct++) macc[ct] = (f32x4){0.f, 0.f, 0.f, 0.f};
#pragma unroll
  for (int ct = 0; ct < 4; ct++){
    macc[ct] = __builtin_amdgcn_mfma_f32_16x16x32_f16(a0, bf0[ct], macc[ct], 0, 0, 0);
    macc[ct] = __builtin_amdgcn_mfma_f32_16x16x32_f16(a1, bf1[ct], macc[ct], 0, 0, 0);
  }

  // ---- bias + softmax + store (C/D: col=mD, row=qD*4+j within 16) ----
#pragma unroll
  for (int j = 0; j < 4; j++){
    int gr = wbase + qD * 4 + j;
    float v[4]; float mx = -INFINITY;
#pragma unroll
    for (int ct = 0; ct < 4; ct++){
      v[ct] = macc[ct][j] + bv[ct];
      mx = fmaxf(mx, v[ct]);
    }
#pragma unroll
    for (int off = 1; off < 16; off <<= 1) mx = fmaxf(mx, __shfl_xor(mx, off, 64));
    float p[4], s = 0.f;
#pragma unroll
    for (int ct = 0; ct < 4; ct++){ p[ct] = __expf(v[ct] - mx); s += p[ct]; }
#pragma unroll
    for (int off = 1; off < 16; off <<= 1) s += __shfl_xor(s, off, 64);
    if (gr < n){
      if (FINAL){
        float ls = __logf(s);
#pragma unroll
        for (int ct = 0; ct < 4; ct++)
          outf[(size_t)gr * 64 + 16 * ct + mD] = v[ct] - mx - ls;
      } else {
        float is = 255.f / s;
#pragma unroll
        for (int ct = 0; ct < 4; ct++)
          outu[(size_t)gr * 64 + 16 * ct + mD] =
              (unsigned char)(int)(p[ct] * is + 0.5f);
      }
    }
  }
}

// ---------------- launch ----------------
extern "C" void kernel_launch(void* const* d_in, const int* in_sizes, int n_in,
                              void* d_out, int out_size, void* d_ws, size_t ws_size,
                              hipStream_t stream) {
  const float* feat = (const float*)d_in[0];
  const int*   src  = (const int*)d_in[1];
  const int*   dst  = (const int*)d_in[2];
  const float* W0   = (const float*)d_in[3];
  const float* al0  = (const float*)d_in[4];
  const float* ar0  = (const float*)d_in[5];
  const float* W1   = (const float*)d_in[6];
  const float* al1  = (const float*)d_in[7];
  const float* ar1  = (const float*)d_in[8];
  const float* W2   = (const float*)d_in[9];
  const float* al2  = (const float*)d_in[10];
  const float* ar2  = (const float*)d_in[11];
  const float* Wp   = (const float*)d_in[12];
  const float* bp   = (const float*)d_in[13];
  float* out = (float*)d_out;

  const int N = in_sizes[0] / 256;
  const int E = in_sizes[1];
  const int NB = (N + 127) / 128;

  char* p = (char*)d_ws;
  auto carve = [&](size_t bytes) -> void* {
    void* r = (void*)p;
    p += (bytes + 255) & ~(size_t)255;
    return r;
  };
  int*   ptr_i = (int*)carve((size_t)(N + 1) * 4);
  int*   bsum  = (int*)carve((size_t)NB * 4);
  int*   bb    = (int*)carve((size_t)(NB + 1) * 4);
  int*   gcur  = (int*)carve((size_t)NB * 4);
  int*   srcs  = (int*)carve((size_t)E * 4);
  float* wE    = (float*)carve((size_t)E * 4);
  int2*  epk   = (int2*)carve((size_t)E * 8);
  half_t* hb   = (half_t*)carve((size_t)N * 128 * 2);
  half_t* xb   = (half_t*)carve((size_t)N * 128 * 2);
  float* el    = (float*)carve((size_t)N * 4 * 4);
  float* er    = (float*)carve((size_t)N * 4 * 4);
  unsigned char* pbA = (unsigned char*)carve((size_t)N * 64);
  unsigned char* pbB = (unsigned char*)carve((size_t)N * 64);
  half_t* T0   = (half_t*)carve(32768 * 2);
  half_t* T1   = (half_t*)carve(16384 * 2);
  half_t* T2   = (half_t*)carve(8192 * 2);
  half_t* Tp   = (half_t*)carve(4096 * 2);
  int2* ebuf = epk;
  (void)ws_size; (void)n_in; (void)out_size;

  // ---- bucketed CSR build + weight conversion ----
  const int EB = (E + 2047) / 2048;
  k_zerob<<<(NB + 255) / 256, 256, 0, stream>>>(bsum, NB);
  kb_hist<<<EB, 256, 0, stream>>>(dst, bsum, E, NB);
  kb_scan<<<1, 512, 0, stream>>>(bsum, bb, gcur, E, NB);
  kb_scat<<<EB, 256, 0, stream>>>(src, dst, gcur, ebuf, E, NB);
  kb_sort<<<NB, 256, 0, stream>>>(ebuf, bb, ptr_i, srcs, N, E);
  k_cvtw<<<240, 256, 0, stream>>>(W0, W1, W2, Wp, T0, T1, T2, Tp);

  const int GG = (N + 63) / 64;
  const int GE = (N + 3) / 4;
  // ---- layer 0: 256 -> [4,32] ----
  k_gemm_m<128, 4, true><<<GG, 256, 0, stream>>>(feat, T0, al0, ar0, hb, el, er, N, 256);
  k_edge<4, 128, 0><<<GE, 256, 0, stream>>>(ptr_i, srcs, (const char*)hb, el, er,
                                            xb, nullptr, wE, nullptr, 1, N);
  // ---- layer 1: 128 -> [4,32] ----
  k_gemm_m<128, 4, false><<<GG, 256, 0, stream>>>(xb, T1, al1, ar1, hb, el, er, N, 128);
  k_edge<4, 128, 0><<<GE, 256, 0, stream>>>(ptr_i, srcs, (const char*)hb, el, er,
                                            xb, nullptr, wE, nullptr, 0, N);
  // ---- layer 2: 128 -> [1,64] (writes u8 pseudo + epk) ----
  k_gemm_m<64, 1, false><<<GG, 256, 0, stream>>>(xb, T2, al2, ar2, hb, el, er, N, 128);
  k_edge<1, 64, 1><<<GE, 256, 0, stream>>>(ptr_i, srcs, (const char*)hb, el, er,
                                           nullptr, pbA, wE, epk, 0, N);

  // ---- 10 LP steps (wave-autonomous kernel) ----
  unsigned char* cur = pbA; unsigned char* nxt = pbB;
  for (int st = 0; st < 10; st++){
    if (st == 9)
      k_lpw<1><<<GG, 256, 0, stream>>>(ptr_i, epk, cur, Tp, bp, nullptr, out, N);
    else
      k_lpw<0><<<GG, 256, 0, stream>>>(ptr_i, epk, cur, Tp, bp, nxt, nullptr, N);
    unsigned char* t = cur; cur = nxt; nxt = t;
  }
}

// Round 15
// 469.466 us; speedup vs baseline: 2.5763x; 1.1123x over previous
//
#include <hip/hip_runtime.h>
#include <math.h>

typedef _Float16 half_t;
typedef __attribute__((ext_vector_type(2))) _Float16 half2t;
typedef __attribute__((ext_vector_type(8))) _Float16 half8;
typedef __attribute__((ext_vector_type(4))) float f32x4;

// ---------------- fp16 helpers ----------------
__device__ __forceinline__ half2t u2h2(unsigned u){ half2t h; __builtin_memcpy(&h, &u, 4); return h; }
__device__ __forceinline__ unsigned h22u(half2t h){ unsigned u; __builtin_memcpy(&u, &h, 4); return u; }
__device__ __forceinline__ unsigned packh2(float a, float b){
  half2t h; h[0] = (_Float16)a; h[1] = (_Float16)b; return h22u(h);
}

// ---------------- wave helpers (wave = 64 on gfx950) ----------------
__device__ __forceinline__ float wsumf(float v){
#pragma unroll
  for (int off = 1; off < 64; off <<= 1) v += __shfl_xor(v, off, 64);
  return v;
}

// ================= bucketed CSR build =================
__global__ void k_zerob(int* __restrict__ a, int n){
  int i = blockIdx.x * blockDim.x + threadIdx.x;
  if (i < n) a[i] = 0;
}

__global__ __launch_bounds__(256) void kb_hist(
    const int* __restrict__ dst, int* __restrict__ bsum, int E, int NB)
{
  __shared__ int cnt[512];
  int t = threadIdx.x;
  int e00 = blockIdx.x * 2048;
  for (int i = t; i < NB; i += 256) cnt[i] = 0;
  __syncthreads();
#pragma unroll
  for (int k = 0; k < 8; k++){
    int e = e00 + 256 * k + t;
    if (e < E) atomicAdd(&cnt[dst[e] >> 7], 1);
  }
  __syncthreads();
  for (int i = t; i < NB; i += 256){
    int c = cnt[i];
    if (c) atomicAdd(&bsum[i], c);
  }
}

__global__ __launch_bounds__(512) void kb_scan(
    const int* __restrict__ bsum, int* __restrict__ bb, int* __restrict__ gcur,
    int E, int NB)
{
  __shared__ int sh[512];
  int t = threadIdx.x;
  int v = (t < NB) ? bsum[t] : 0;
  sh[t] = v; __syncthreads();
  for (int s = 1; s < 512; s <<= 1){
    int u = (t >= s) ? sh[t - s] : 0;
    __syncthreads();
    sh[t] += u;
    __syncthreads();
  }
  if (t < NB){
    int ex = sh[t] - v;
    bb[t] = ex; gcur[t] = ex;
  }
  if (t == 0) bb[NB] = E;
}

__global__ __launch_bounds__(256) void kb_scat(
    const int* __restrict__ src, const int* __restrict__ dst,
    int* __restrict__ gcur, int2* __restrict__ ebuf, int E, int NB)
{
  __shared__ int cnt[512], base[512];
  int t = threadIdx.x;
  int e00 = blockIdx.x * 2048;
  for (int i = t; i < NB; i += 256) cnt[i] = 0;
  __syncthreads();
  int bk[8], sv[8], dv[8];
#pragma unroll
  for (int k = 0; k < 8; k++){
    int e = e00 + 256 * k + t;
    if (e < E){
      dv[k] = dst[e]; sv[k] = src[e];
      bk[k] = dv[k] >> 7;
      atomicAdd(&cnt[bk[k]], 1);
    } else bk[k] = -1;
  }
  __syncthreads();
  for (int i = t; i < NB; i += 256){
    int c = cnt[i];
    base[i] = c ? atomicAdd(&gcur[i], c) : 0;
    cnt[i] = 0;
  }
  __syncthreads();
#pragma unroll
  for (int k = 0; k < 8; k++){
    if (bk[k] >= 0){
      int pos = base[bk[k]] + atomicAdd(&cnt[bk[k]], 1);
      ebuf[pos] = make_int2(sv[k], dv[k]);
    }
  }
}

__global__ __launch_bounds__(256) void kb_sort(
    const int2* __restrict__ ebuf, const int* __restrict__ bb,
    int* __restrict__ ptre, int* __restrict__ srcs, int N, int E)
{
  __shared__ int cnt[128], off[128];
  int b = blockIdx.x, t = threadIdx.x;
  int e0 = bb[b], e1 = bb[b + 1];
  int nn0 = b << 7;
  if (t < 128) cnt[t] = 0;
  __syncthreads();
  for (int e = e0 + t; e < e1; e += 256)
    atomicAdd(&cnt[ebuf[e].y & 127], 1);
  __syncthreads();
  if (t < 128) off[t] = cnt[t];
  __syncthreads();
  for (int s = 1; s < 128; s <<= 1){
    int v = (t < 128 && t >= s) ? off[t - s] : 0;
    __syncthreads();
    if (t < 128) off[t] += v;
    __syncthreads();
  }
  if (t < 128){
    int ex = off[t] - cnt[t];
    off[t] = ex;
    int node = nn0 + t;
    if (node < N) ptre[node] = e0 + ex;
    cnt[t] = 0;
  }
  if (b == (int)gridDim.x - 1 && t == 0) ptre[N] = E;
  __syncthreads();
  for (int e = e0 + t; e < e1; e += 256){
    int2 ed = ebuf[e];
    int lo = ed.y & 127;
    int pos = atomicAdd(&cnt[lo], 1);
    srcs[e0 + off[lo] + pos] = ed.x;
  }
}

// ---------------- weight convert + transpose to fp16 [N][K] ----------------
__global__ void k_cvtw(const float* __restrict__ W0, const float* __restrict__ W1,
                       const float* __restrict__ W2, const float* __restrict__ Wp,
                       half_t* __restrict__ T0, half_t* __restrict__ T1,
                       half_t* __restrict__ T2, half_t* __restrict__ Tp){
  int i = blockIdx.x * 256 + threadIdx.x;
  const float* src; half_t* dst; int NN, KK, idx;
  if (i < 32768){ src = W0; dst = T0; NN = 128; KK = 256; idx = i; }
  else if (i < 49152){ src = W1; dst = T1; NN = 128; KK = 128; idx = i - 32768; }
  else if (i < 57344){ src = W2; dst = T2; NN = 64; KK = 128; idx = i - 49152; }
  else { src = Wp; dst = Tp; NN = 64; KK = 64; idx = i - 57344; }
  int nn = idx / KK, kk = idx - nn * KK;
  dst[idx] = (_Float16)src[(size_t)kk * NN + nn];
}

// ---------------- MFMA GEMM + fused el/er epilogue --------------------------
template<int NC, int NH, bool XF32>
__global__ __launch_bounds__(256) void k_gemm_m(
    const void* __restrict__ Xv, const half_t* __restrict__ Wt,
    const float* __restrict__ al, const float* __restrict__ ar,
    half_t* __restrict__ Yh, float* __restrict__ el, float* __restrict__ er,
    int n, int KD)
{
  constexpr int CT = NC / 16;
  __shared__ __align__(16) half_t xs[64 * 72];
  __shared__ __align__(16) half_t ws[NC * 72];
  int tid = threadIdx.x;
  int w = tid >> 6, lane = tid & 63;
  int m = lane & 15, q = lane >> 4;
  int n0 = blockIdx.x * 64;
  f32x4 acc[CT];
#pragma unroll
  for (int ct = 0; ct < CT; ct++) acc[ct] = (f32x4){0.f, 0.f, 0.f, 0.f};

  for (int kc = 0; kc < KD; kc += 64){
    if (XF32){
      const float* X = (const float*)Xv;
#pragma unroll
      for (int s = tid; s < 512; s += 256){
        int r = s >> 3, off = (s & 7) * 8;
        int gr = min(n0 + r, n - 1);
        const float4* g = (const float4*)(X + (size_t)gr * KD + kc + off);
        float4 v0 = g[0], v1 = g[1];
        uint4 pk = make_uint4(packh2(v0.x, v0.y), packh2(v0.z, v0.w),
                              packh2(v1.x, v1.y), packh2(v1.z, v1.w));
        *(uint4*)&xs[r * 72 + off] = pk;
      }
    } else {
      const half_t* X = (const half_t*)Xv;
#pragma unroll
      for (int s = tid; s < 512; s += 256){
        int r = s >> 3, off = (s & 7) * 8;
        int gr = min(n0 + r, n - 1);
        *(uint4*)&xs[r * 72 + off] = *(const uint4*)(X + (size_t)gr * KD + kc + off);
      }
    }
#pragma unroll
    for (int s = tid; s < NC * 8; s += 256){
      int r = s >> 3, off = (s & 7) * 8;
      *(uint4*)&ws[r * 72 + off] = *(const uint4*)(Wt + (size_t)r * KD + kc + off);
    }
    __syncthreads();
    half8 a0 = *(const half8*)&xs[(16 * w + m) * 72 + q * 8];
    half8 a1 = *(const half8*)&xs[(16 * w + m) * 72 + 32 + q * 8];
#pragma unroll
    for (int ct = 0; ct < CT; ct++){
      half8 b0 = *(const half8*)&ws[(16 * ct + m) * 72 + q * 8];
      half8 b1 = *(const half8*)&ws[(16 * ct + m) * 72 + 32 + q * 8];
      acc[ct] = __builtin_amdgcn_mfma_f32_16x16x32_f16(a0, b0, acc[ct], 0, 0, 0);
      acc[ct] = __builtin_amdgcn_mfma_f32_16x16x32_f16(a1, b1, acc[ct], 0, 0, 0);
    }
    __syncthreads();
  }

#pragma unroll
  for (int j = 0; j < 4; j++){
    int gr = n0 + 16 * w + q * 4 + j;
    if (gr < n){
#pragma unroll
      for (int ct = 0; ct < CT; ct++)
        Yh[(size_t)gr * NC + 16 * ct + m] = (_Float16)acc[ct][j];
    }
  }
  float alv[CT], arv[CT];
#pragma unroll
  for (int ct = 0; ct < CT; ct++){ alv[ct] = al[16 * ct + m]; arv[ct] = ar[16 * ct + m]; }
#pragma unroll
  for (int j = 0; j < 4; j++){
    int gr = n0 + 16 * w + q * 4 + j;
    float ev[NH], rv[NH];
    if (NH == 4){
#pragma unroll
      for (int hh = 0; hh < 4; hh++){
        ev[hh] = acc[2 * hh][j] * alv[2 * hh] + acc[2 * hh + 1][j] * alv[2 * hh + 1];
        rv[hh] = acc[2 * hh][j] * arv[2 * hh] + acc[2 * hh + 1][j] * arv[2 * hh + 1];
      }
    } else {
      ev[0] = 0.f; rv[0] = 0.f;
#pragma unroll
      for (int ct = 0; ct < CT; ct++){
        ev[0] += acc[ct][j] * alv[ct];
        rv[0] += acc[ct][j] * arv[ct];
      }
    }
#pragma unroll
    for (int off = 1; off < 16; off <<= 1){
#pragma unroll
      for (int hh = 0; hh < NH; hh++){
        ev[hh] += __shfl_xor(ev[hh], off, 64);
        rv[hh] += __shfl_xor(rv[hh], off, 64);
      }
    }
    if (m == 0 && gr < n){
#pragma unroll
      for (int hh = 0; hh < NH; hh++){
        el[(size_t)gr * NH + hh] = ev[hh];
        er[(size_t)gr * NH + hh] = rv[hh];
      }
    }
  }
}

// ---------------- edge softmax + aggregation (round-11 structure) -----------
// EPI 1 now writes a PACKED u32 descriptor: low16 = src id, high16 = w*65535.
template<int HNUM, int MDIM, int EPI>
__global__ __launch_bounds__(256) void k_edge(
    const int* __restrict__ ptre, const int* __restrict__ srcs,
    const char* __restrict__ hb, const float* __restrict__ el,
    const float* __restrict__ er, half_t* __restrict__ outx,
    unsigned char* __restrict__ outu, float* __restrict__ wE,
    unsigned* __restrict__ epk, int init_w, int n)
{
  constexpr int LL = MDIM / 8;
  constexpr int EP = 64 / LL;
  constexpr int RB = MDIM * 2;
  int node = blockIdx.x * 4 + (threadIdx.x >> 6);
  if (node >= n) return;
  int lane = threadIdx.x & 63;
  int base = ptre[node], deg = ptre[node + 1] - base;

  float erv[HNUM];
  if (HNUM == 4){
    float4 t = *reinterpret_cast<const float4*>(er + node * 4);
    erv[0] = t.x; erv[1] = t.y; erv[2] = t.z; erv[3] = t.w;
  } else erv[0] = er[node];

  int l = lane % LL, g = lane / LL;
  int hidx = l >> 2;
  int bo = 16 * l;
  half2t acc2[4];
#pragma unroll
  for (int k = 0; k < 4; k++) acc2[k] = (half2t){(_Float16)0.f, (_Float16)0.f};

  float inv[HNUM];
  if (deg > 64){
    float sm[HNUM];
#pragma unroll
    for (int h = 0; h < HNUM; h++) sm[h] = 0.f;
    for (int i = lane; i < deg; i += 64){
      int s = srcs[base + i];
      float e[HNUM];
      if (HNUM == 4){
        float4 t = *reinterpret_cast<const float4*>(el + s * 4);
        e[0] = t.x; e[1] = t.y; e[2] = t.z; e[3] = t.w;
      } else e[0] = el[s];
#pragma unroll
      for (int h = 0; h < HNUM; h++){
        float v = e[h] + erv[h];
        v = v > 0.f ? v : 0.2f * v;
        sm[h] += __expf(v);
      }
    }
#pragma unroll
    for (int h = 0; h < HNUM; h++) inv[h] = 1.f / (wsumf(sm[h]) + 1e-9f);
  }

  for (int c0 = 0; c0 < deg; c0 += 64){
    int cnt = min(64, deg - c0);
    int soff = 0; unsigned pa = 0, pb2 = 0;
    float pv[HNUM];
    int s = 0;
    if (lane < cnt){
      s = srcs[base + c0 + lane];
      float e[HNUM];
      if (HNUM == 4){
        float4 t = *reinterpret_cast<const float4*>(el + s * 4);
        e[0] = t.x; e[1] = t.y; e[2] = t.z; e[3] = t.w;
      } else e[0] = el[s];
#pragma unroll
      for (int h = 0; h < HNUM; h++){
        float v = e[h] + erv[h];
        v = v > 0.f ? v : 0.2f * v;
        pv[h] = __expf(v);
      }
    } else {
#pragma unroll
      for (int h = 0; h < HNUM; h++) pv[h] = 0.f;
    }
    if (deg <= 64){
#pragma unroll
      for (int h = 0; h < HNUM; h++) inv[h] = 1.f / (wsumf(pv[h]) + 1e-9f);
    }
    if (lane < cnt){
      float a[HNUM], wsum = 0.f;
#pragma unroll
      for (int h = 0; h < HNUM; h++){ a[h] = pv[h] * inv[h]; wsum += a[h]; }
      if (HNUM == 4){ pa = packh2(a[0], a[1]); pb2 = packh2(a[2], a[3]); }
      else pa = packh2(a[0], a[0]);
      wsum *= (1.f / (3.f * HNUM));
      int eidx = base + c0 + lane;
      if (EPI == 1){
        float wtot = wE[eidx] + wsum;                 // in (0,1]
        unsigned w16 = (unsigned)(int)(wtot * 65535.f + 0.5f);
        if (w16 > 65535u) w16 = 65535u;
        epk[eidx] = (unsigned)s | (w16 << 16);
      } else {
        wE[eidx] = init_w ? wsum : (wE[eidx] + wsum);
      }
      soff = s * RB;
    }
    for (int j0 = 0; j0 < cnt; j0 += EP){
      int j = j0 + g;
      int so = __shfl(soff, j, 64);
      unsigned paj = (unsigned)__shfl((int)pa, j, 64);
      unsigned pbj = 0;
      if (HNUM == 4) pbj = (unsigned)__shfl((int)pb2, j, 64);
      if (j < cnt){
        unsigned a2u;
        if (HNUM == 4){
          unsigned sel = (hidx < 2) ? paj : pbj;
          unsigned hb16 = (hidx & 1) ? (sel >> 16) : (sel & 0xffffu);
          a2u = hb16 | (hb16 << 16);
        } else a2u = paj;
        half2t a2 = u2h2(a2u);
        uint4 v = *(const uint4*)(hb + (unsigned)so + bo);
        acc2[0] += a2 * u2h2(v.x);
        acc2[1] += a2 * u2h2(v.y);
        acc2[2] += a2 * u2h2(v.z);
        acc2[3] += a2 * u2h2(v.w);
      }
    }
  }

#pragma unroll
  for (int off = LL; off < 64; off <<= 1)
#pragma unroll
    for (int k = 0; k < 4; k++)
      acc2[k] += u2h2((unsigned)__shfl_xor((int)h22u(acc2[k]), off, 64));

  float o[8];
#pragma unroll
  for (int k = 0; k < 4; k++){
    o[2 * k] = (float)acc2[k][0];
    o[2 * k + 1] = (float)acc2[k][1];
  }
  if (EPI == 0){
    if (g == 0){
#pragma unroll
      for (int d = 0; d < 8; d++) o[d] = o[d] > 0.f ? o[d] : expm1f(o[d]);
      uint4 pk = make_uint4(packh2(o[0], o[1]), packh2(o[2], o[3]),
                            packh2(o[4], o[5]), packh2(o[6], o[7]));
      reinterpret_cast<uint4*>(outx + (size_t)node * MDIM)[l] = pk;
    }
  } else {
    float m8 = o[0];
#pragma unroll
    for (int d = 1; d < 8; d++) m8 = fmaxf(m8, o[d]);
#pragma unroll
    for (int off = 1; off < 8; off <<= 1) m8 = fmaxf(m8, __shfl_xor(m8, off, 64));
    float p[8], s8 = 0.f;
#pragma unroll
    for (int d = 0; d < 8; d++){ p[d] = __expf(o[d] - m8); s8 += p[d]; }
#pragma unroll
    for (int off = 1; off < 8; off <<= 1) s8 += __shfl_xor(s8, off, 64);
    float is = 255.f / s8;
    if (g == 0){
      unsigned b0 = 0, b1 = 0;
#pragma unroll
      for (int d = 0; d < 4; d++) b0 |= ((unsigned)(int)(p[d] * is + 0.5f)) << (8 * d);
#pragma unroll
      for (int d = 0; d < 4; d++) b1 |= ((unsigned)(int)(p[4 + d] * is + 0.5f)) << (8 * d);
      *reinterpret_cast<uint2*>(outu + (size_t)node * 64 + 8 * l) = make_uint2(b0, b1);
    }
  }
}

// ---------------- LP step (r11 k_lpu, packed u32 descriptors) ---------------
// 512 thr: 64 nodes/block, 8 lanes/node (2 streams x batch-4), LDS A-tile,
// 64x64 MFMA vs Wp, softmax -> u8 / final log-softmax fp32.
template<int FINAL>
__global__ __launch_bounds__(512) void k_lpu(
    const int* __restrict__ ptre, const unsigned* __restrict__ epk,
    const unsigned char* __restrict__ pb, const half_t* __restrict__ Tp,
    const float* __restrict__ bp, unsigned char* __restrict__ outu,
    float* __restrict__ outf, int n)
{
  constexpr float WC = 1.f / (65535.f * 255.f);
  __shared__ __align__(16) half_t xs[64 * 72];
  __shared__ __align__(16) half_t ws[64 * 72];
  __shared__ float bsh[64];
  int tid = threadIdx.x;
  int w = tid >> 6, lane = tid & 63;
  int n0 = blockIdx.x * 64;
  {
    int r = tid >> 3, off = (tid & 7) * 8;
    *(uint4*)&ws[r * 72 + off] = *(const uint4*)(Tp + r * 64 + off);
  }
  if (tid < 64) bsh[tid] = bp[tid];

  int grp = tid >> 3;
  int l8 = tid & 7;
  int st = l8 >> 2, li = l8 & 3;
  int bo = 16 * li;
  int node = n0 + grp;
  float acc[16];
#pragma unroll
  for (int c = 0; c < 16; c++) acc[c] = 0.f;

  auto accum = [&](uint4 v, float wv){
#pragma unroll
    for (int b = 0; b < 4; b++){
      unsigned u = (&v.x)[b];
      acc[4 * b + 0] += wv * (float)(u & 0xffu);
      acc[4 * b + 1] += wv * (float)((u >> 8) & 0xffu);
      acc[4 * b + 2] += wv * (float)((u >> 16) & 0xffu);
      acc[4 * b + 3] += wv * (float)((u >> 24) & 0xffu);
    }
  };

  if (node < n){
    int base = ptre[node], endd = ptre[node + 1];
    for (int j0 = base + 4 * st; j0 < endd; j0 += 8){
      unsigned ee[4]; float wv[4];
#pragma unroll
      for (int k = 0; k < 4; k++){
        int j = j0 + k;
        ee[k] = epk[min(j, endd - 1)];
        wv[k] = (j < endd) ? (float)(ee[k] >> 16) * WC : 0.f;
      }
      uint4 vv[4];
#pragma unroll
      for (int k = 0; k < 4; k++)
        vv[k] = *(const uint4*)(pb + ((ee[k] & 0xffffu) << 6) + bo);
#pragma unroll
      for (int k = 0; k < 4; k++) accum(vv[k], wv[k]);
    }
  }
#pragma unroll
  for (int c = 0; c < 16; c++) acc[c] += __shfl_xor(acc[c], 4, 64);
  if (st == 0){
    half2t hp[8];
#pragma unroll
    for (int c = 0; c < 8; c++){
      hp[c][0] = (_Float16)acc[2 * c]; hp[c][1] = (_Float16)acc[2 * c + 1];
    }
    *(uint4*)&xs[grp * 72 + 16 * li]     = *(uint4*)&hp[0];
    *(uint4*)&xs[grp * 72 + 16 * li + 8] = *(uint4*)&hp[4];
  }
  __syncthreads();
  if (w >= 4) return;

  int m = lane & 15, q = lane >> 4;
  f32x4 macc[4];
#pragma unroll
  for (int ct = 0; ct < 4; ct++) macc[ct] = (f32x4){0.f, 0.f, 0.f, 0.f};
  half8 a0 = *(const half8*)&xs[(16 * w + m) * 72 + q * 8];
  half8 a1 = *(const half8*)&xs[(16 * w + m) * 72 + 32 + q * 8];
#pragma unroll
  for (int ct = 0; ct < 4; ct++){
    half8 b0 = *(const half8*)&ws[(16 * ct + m) * 72 + q * 8];
    half8 b1 = *(const half8*)&ws[(16 * ct + m) * 72 + 32 + q * 8];
    macc[ct] = __builtin_amdgcn_mfma_f32_16x16x32_f16(a0, b0, macc[ct], 0, 0, 0);
    macc[ct] = __builtin_amdgcn_mfma_f32_16x16x32_f16(a1, b1, macc[ct], 0, 0, 0);
  }

#pragma unroll
  for (int j = 0; j < 4; j++){
    int gr = n0 + 16 * w + q * 4 + j;
    float v[4]; float mx = -INFINITY;
#pragma unroll
    for (int ct = 0; ct < 4; ct++){
      v[ct] = macc[ct][j] + bsh[16 * ct + m];
      mx = fmaxf(mx, v[ct]);
    }
#pragma unroll
    for (int off = 1; off < 16; off <<= 1) mx = fmaxf(mx, __shfl_xor(mx, off, 64));
    float p[4], s = 0.f;
#pragma unroll
    for (int ct = 0; ct < 4; ct++){ p[ct] = __expf(v[ct] - mx); s += p[ct]; }
#pragma unroll
    for (int off = 1; off < 16; off <<= 1) s += __shfl_xor(s, off, 64);
    if (gr < n){
      if (FINAL){
        float ls = __logf(s);
#pragma unroll
        for (int ct = 0; ct < 4; ct++)
          outf[(size_t)gr * 64 + 16 * ct + m] = v[ct] - mx - ls;
      } else {
        float is = 255.f / s;
#pragma unroll
        for (int ct = 0; ct < 4; ct++)
          outu[(size_t)gr * 64 + 16 * ct + m] =
              (unsigned char)(int)(p[ct] * is + 0.5f);
      }
    }
  }
}

// ---------------- launch ----------------
extern "C" void kernel_launch(void* const* d_in, const int* in_sizes, int n_in,
                              void* d_out, int out_size, void* d_ws, size_t ws_size,
                              hipStream_t stream) {
  const float* feat = (const float*)d_in[0];
  const int*   src  = (const int*)d_in[1];
  const int*   dst  = (const int*)d_in[2];
  const float* W0   = (const float*)d_in[3];
  const float* al0  = (const float*)d_in[4];
  const float* ar0  = (const float*)d_in[5];
  const float* W1   = (const float*)d_in[6];
  const float* al1  = (const float*)d_in[7];
  const float* ar1  = (const float*)d_in[8];
  const float* W2   = (const float*)d_in[9];
  const float* al2  = (const float*)d_in[10];
  const float* ar2  = (const float*)d_in[11];
  const float* Wp   = (const float*)d_in[12];
  const float* bp   = (const float*)d_in[13];
  float* out = (float*)d_out;

  const int N = in_sizes[0] / 256;
  const int E = in_sizes[1];
  const int NB = (N + 127) / 128;

  char* p = (char*)d_ws;
  auto carve = [&](size_t bytes) -> void* {
    void* r = (void*)p;
    p += (bytes + 255) & ~(size_t)255;
    return r;
  };
  int*   ptr_i = (int*)carve((size_t)(N + 1) * 4);
  int*   bsum  = (int*)carve((size_t)NB * 4);
  int*   bb    = (int*)carve((size_t)(NB + 1) * 4);
  int*   gcur  = (int*)carve((size_t)NB * 4);
  int*   srcs  = (int*)carve((size_t)E * 4);
  float* wE    = (float*)carve((size_t)E * 4);
  int2*  ebuf  = (int2*)carve((size_t)E * 8);
  unsigned* epk = (unsigned*)ebuf;   // packed u32 descriptors overlay ebuf
  half_t* hb   = (half_t*)carve((size_t)N * 128 * 2);
  half_t* xb   = (half_t*)carve((size_t)N * 128 * 2);
  float* el    = (float*)carve((size_t)N * 4 * 4);
  float* er    = (float*)carve((size_t)N * 4 * 4);
  unsigned char* pbA = (unsigned char*)carve((size_t)N * 64);
  unsigned char* pbB = (unsigned char*)carve((size_t)N * 64);
  half_t* T0   = (half_t*)carve(32768 * 2);
  half_t* T1   = (half_t*)carve(16384 * 2);
  half_t* T2   = (half_t*)carve(8192 * 2);
  half_t* Tp   = (half_t*)carve(4096 * 2);
  (void)ws_size; (void)n_in; (void)out_size;

  // ---- bucketed CSR build + weight conversion ----
  const int EB = (E + 2047) / 2048;
  k_zerob<<<(NB + 255) / 256, 256, 0, stream>>>(bsum, NB);
  kb_hist<<<EB, 256, 0, stream>>>(dst, bsum, E, NB);
  kb_scan<<<1, 512, 0, stream>>>(bsum, bb, gcur, E, NB);
  kb_scat<<<EB, 256, 0, stream>>>(src, dst, gcur, ebuf, E, NB);
  kb_sort<<<NB, 256, 0, stream>>>(ebuf, bb, ptr_i, srcs, N, E);
  k_cvtw<<<240, 256, 0, stream>>>(W0, W1, W2, Wp, T0, T1, T2, Tp);

  const int GG = (N + 63) / 64;
  const int GE = (N + 3) / 4;
  // ---- layer 0: 256 -> [4,32] ----
  k_gemm_m<128, 4, true><<<GG, 256, 0, stream>>>(feat, T0, al0, ar0, hb, el, er, N, 256);
  k_edge<4, 128, 0><<<GE, 256, 0, stream>>>(ptr_i, srcs, (const char*)hb, el, er,
                                            xb, nullptr, wE, nullptr, 1, N);
  // ---- layer 1: 128 -> [4,32] ----
  k_gemm_m<128, 4, false><<<GG, 256, 0, stream>>>(xb, T1, al1, ar1, hb, el, er, N, 128);
  k_edge<4, 128, 0><<<GE, 256, 0, stream>>>(ptr_i, srcs, (const char*)hb, el, er,
                                            xb, nullptr, wE, nullptr, 0, N);
  // ---- layer 2: 128 -> [1,64] (writes u8 pseudo + packed epk) ----
  // NOTE: epk overlays ebuf, which is dead after kb_sort.
  k_gemm_m<64, 1, false><<<GG, 256, 0, stream>>>(xb, T2, al2, ar2, hb, el, er, N, 128);
  k_edge<1, 64, 1><<<GE, 256, 0, stream>>>(ptr_i, srcs, (const char*)hb, el, er,
                                           nullptr, pbA, wE, epk, 0, N);

  // ---- 10 LP steps (u32 descriptors) ----
  unsigned char* cur = pbA; unsigned char* nxt = pbB;
  for (int st = 0; st < 10; st++){
    if (st == 9)
      k_lpu<1><<<GG, 512, 0, stream>>>(ptr_i, epk, cur, Tp, bp, nullptr, out, N);
    else
      k_lpu<0><<<GG, 512, 0, stream>>>(ptr_i, epk, cur, Tp, bp, nxt, nullptr, N);
    unsigned char* t = cur; cur = nxt; nxt = t;
  }
}